// Round 1
// baseline (461.713 us; speedup 1.0000x reference)
//
#include <hip/hip_runtime.h>
#include <stdint.h>

#define NN 100000
#define NE 1600000
#define DIN 500
#define DH 64
#define DOUT 8
#define KP 512          // K padded to 16 mfma steps of 32
#define MAXDEG 64       // P(in-deg+self >= 64) ~ 1e-19 for Poisson(16)

typedef __attribute__((ext_vector_type(8))) short short8;
typedef __attribute__((ext_vector_type(4))) float f32x4;
typedef unsigned short ushort_t;

static __device__ __forceinline__ ushort_t f2bf(float f) {
  union { float f; uint32_t u; } v; v.f = f;
  uint32_t u = v.u;
  return (ushort_t)((u + 0x7FFFu + ((u >> 16) & 1u)) >> 16);  // RTN-even
}
static __device__ __forceinline__ float bf2f(ushort_t h) {
  union { uint32_t u; float f; } v; v.u = ((uint32_t)h) << 16;
  return v.f;
}

// Build fixed-stride reverse adjacency: colsrc[d*64 + slot] = s, cursor[d]=deg(incl self)
__global__ __launch_bounds__(256) void k_fill(const int* __restrict__ ei,
                                              int* __restrict__ cursor,
                                              int* __restrict__ colsrc) {
  int id = blockIdx.x * 256 + threadIdx.x;
  if (id >= NE + NN) return;
  int s, d;
  if (id < NE) { s = ei[id]; d = ei[NE + id]; }
  else { s = id - NE; d = s; }                 // self-loops
  int pos = atomicAdd(&cursor[d], 1);
  if (pos < MAXDEG) colsrc[d * MAXDEG + pos] = s;
}

__global__ __launch_bounds__(256) void k_dinv(const int* __restrict__ cursor,
                                              float* __restrict__ dinv) {
  int v = blockIdx.x * 256 + threadIdx.x;
  if (v >= NN) return;
  dinv[v] = 1.0f / sqrtf((float)cursor[v]);    // deg >= 1 always (self-loop)
}

// W1 [500][64] fp32 -> transposed, K-padded bf16 hi/lo split: bh/bl[n*512 + k]
__global__ __launch_bounds__(256) void k_w1cvt(const float* __restrict__ W1,
                                               ushort_t* __restrict__ bh,
                                               ushort_t* __restrict__ bl) {
  int id = blockIdx.x * 256 + threadIdx.x;
  if (id >= DH * KP) return;
  int n = id >> 9, k = id & (KP - 1);
  float v = (k < DIN) ? W1[k * DH + n] : 0.0f;
  ushort_t hi = f2bf(v);
  bh[id] = hi;
  bl[id] = f2bf(v - bf2f(hi));
}

// hw = x @ W1  via bf16 MFMA with 3-term split (fp32-accurate). One wave = 16 rows x 64 cols.
__global__ __launch_bounds__(256) void k_gemm1(const float* __restrict__ x,
                                               const ushort_t* __restrict__ bh,
                                               const ushort_t* __restrict__ bl,
                                               float* __restrict__ hw) {
  int lane = threadIdx.x & 63;
  int wid = blockIdx.x * 4 + (threadIdx.x >> 6);
  if (wid >= NN / 16) return;
  int r = lane & 15;        // A-row / B-col / D-col within tile
  int g = lane >> 4;        // k-group (8 k each)
  int row0 = wid * 16;
  const float* xrow = x + (size_t)(row0 + r) * DIN;   // row*2000B is 16B-aligned

  f32x4 acc0 = {0,0,0,0}, acc1 = {0,0,0,0}, acc2 = {0,0,0,0}, acc3 = {0,0,0,0};

  for (int kk = 0; kk < 16; ++kk) {
    int kb = kk * 32 + g * 8;
    float a[8];
    if (kk < 15) {
      float4 v0 = *(const float4*)(xrow + kb);
      float4 v1 = *(const float4*)(xrow + kb + 4);
      a[0] = v0.x; a[1] = v0.y; a[2] = v0.z; a[3] = v0.w;
      a[4] = v1.x; a[5] = v1.y; a[6] = v1.z; a[7] = v1.w;
    } else {
#pragma unroll
      for (int i = 0; i < 8; ++i) { int k = kb + i; a[i] = (k < DIN) ? xrow[k] : 0.0f; }
    }
    short8 ah, al;
#pragma unroll
    for (int i = 0; i < 8; ++i) {
      ushort_t hi = f2bf(a[i]);
      ah[i] = (short)hi;
      al[i] = (short)f2bf(a[i] - bf2f(hi));
    }
    const ushort_t* bhp = bh + r * KP + kb;
    const ushort_t* blp = bl + r * KP + kb;
#define TILE(T, OFF)                                                            \
    {                                                                           \
      short8 bhf = *(const short8*)(bhp + (OFF) * 16 * KP);                     \
      short8 blf = *(const short8*)(blp + (OFF) * 16 * KP);                     \
      T = __builtin_amdgcn_mfma_f32_16x16x32_bf16(ah, bhf, T, 0, 0, 0);         \
      T = __builtin_amdgcn_mfma_f32_16x16x32_bf16(al, bhf, T, 0, 0, 0);         \
      T = __builtin_amdgcn_mfma_f32_16x16x32_bf16(ah, blf, T, 0, 0, 0);         \
    }
    TILE(acc0, 0) TILE(acc1, 1) TILE(acc2, 2) TILE(acc3, 3)
#undef TILE
  }
#pragma unroll
  for (int i = 0; i < 4; ++i) {
    int orow = row0 + g * 4 + i;          // C/D: row=(lane>>4)*4+reg, col=lane&15
    float* o = hw + (size_t)orow * DH + r;
    o[0]  = acc0[i];
    o[16] = acc1[i];
    o[32] = acc2[i];
    o[48] = acc3[i];
  }
}

// Layer-1 aggregate (gather) + bias + ReLU + fused h@W2 -> hw2[v][0..7]
__global__ __launch_bounds__(256) void k_agg1(const float* __restrict__ hw,
                                              const int* __restrict__ colsrc,
                                              const int* __restrict__ cnt,
                                              const float* __restrict__ dinv,
                                              const float* __restrict__ b1,
                                              const float* __restrict__ W2,
                                              float* __restrict__ hw2) {
  int lane = threadIdx.x & 63;
  int v = blockIdx.x * 4 + (threadIdx.x >> 6);
  if (v >= NN) return;
  int c = cnt[v]; if (c > MAXDEG) c = MAXDEG;
  float dv = dinv[v];
  const int* cl = colsrc + v * MAXDEG;
  float acc = 0.0f;
  for (int i = 0; i < c; ++i) {
    int s = __builtin_amdgcn_readfirstlane(cl[i]);
    float nrm = dinv[s] * dv;
    acc = fmaf(hw[(size_t)s * DH + lane], nrm, acc);   // 256B coalesced per edge
  }
  float h = acc + b1[lane];
  h = h > 0.0f ? h : 0.0f;
  // fused 64->8 transform: p_j = sum_lane h[lane] * W2[lane][j]
  const float* w2r = W2 + lane * DOUT;
  float p0 = h * w2r[0], p1 = h * w2r[1], p2 = h * w2r[2], p3 = h * w2r[3];
  float p4 = h * w2r[4], p5 = h * w2r[5], p6 = h * w2r[6], p7 = h * w2r[7];
#pragma unroll
  for (int off = 32; off > 0; off >>= 1) {
    p0 += __shfl_xor(p0, off); p1 += __shfl_xor(p1, off);
    p2 += __shfl_xor(p2, off); p3 += __shfl_xor(p3, off);
    p4 += __shfl_xor(p4, off); p5 += __shfl_xor(p5, off);
    p6 += __shfl_xor(p6, off); p7 += __shfl_xor(p7, off);
  }
  if (lane == 0) {
    float4 q0 = {p0, p1, p2, p3}, q1 = {p4, p5, p6, p7};
    *(float4*)(hw2 + (size_t)v * DOUT)     = q0;
    *(float4*)(hw2 + (size_t)v * DOUT + 4) = q1;
  }
}

// Layer-2 aggregate + bias + log_softmax. One thread per node.
__global__ __launch_bounds__(256) void k_agg2(const float* __restrict__ hw2,
                                              const int* __restrict__ colsrc,
                                              const int* __restrict__ cnt,
                                              const float* __restrict__ dinv,
                                              const float* __restrict__ b2,
                                              float* __restrict__ out) {
  int v = blockIdx.x * 256 + threadIdx.x;
  if (v >= NN) return;
  int c = cnt[v]; if (c > MAXDEG) c = MAXDEG;
  float dv = dinv[v];
  const int* cl = colsrc + v * MAXDEG;
  float a0 = 0, a1 = 0, a2 = 0, a3 = 0, a4 = 0, a5 = 0, a6 = 0, a7 = 0;
  for (int i = 0; i < c; ++i) {
    int s = cl[i];
    float nrm = dinv[s] * dv;
    const float4* p = (const float4*)(hw2 + (size_t)s * DOUT);
    float4 u = p[0], w = p[1];
    a0 = fmaf(u.x, nrm, a0); a1 = fmaf(u.y, nrm, a1);
    a2 = fmaf(u.z, nrm, a2); a3 = fmaf(u.w, nrm, a3);
    a4 = fmaf(w.x, nrm, a4); a5 = fmaf(w.y, nrm, a5);
    a6 = fmaf(w.z, nrm, a6); a7 = fmaf(w.w, nrm, a7);
  }
  a0 += b2[0]; a1 += b2[1]; a2 += b2[2]; a3 += b2[3];
  a4 += b2[4]; a5 += b2[5]; a6 += b2[6]; a7 += b2[7];
  float m = fmaxf(fmaxf(fmaxf(a0, a1), fmaxf(a2, a3)),
                  fmaxf(fmaxf(a4, a5), fmaxf(a6, a7)));
  float sum = expf(a0 - m) + expf(a1 - m) + expf(a2 - m) + expf(a3 - m) +
              expf(a4 - m) + expf(a5 - m) + expf(a6 - m) + expf(a7 - m);
  float ls = m + logf(sum);
  float4 o0 = {a0 - ls, a1 - ls, a2 - ls, a3 - ls};
  float4 o1 = {a4 - ls, a5 - ls, a6 - ls, a7 - ls};
  *(float4*)(out + (size_t)v * DOUT)     = o0;
  *(float4*)(out + (size_t)v * DOUT + 4) = o1;
}

extern "C" void kernel_launch(void* const* d_in, const int* in_sizes, int n_in,
                              void* d_out, int out_size, void* d_ws, size_t ws_size,
                              hipStream_t stream) {
  const float* x  = (const float*)d_in[0];
  const int*   ei = (const int*)d_in[1];
  const float* W1 = (const float*)d_in[2];
  const float* b1 = (const float*)d_in[3];
  const float* W2 = (const float*)d_in[4];
  const float* b2 = (const float*)d_in[5];
  float* out = (float*)d_out;

  char* w = (char*)d_ws;
  size_t off = 0;
  auto alloc = [&](size_t bytes) {
    char* p = w + off;
    off += (bytes + 255) & ~(size_t)255;
    return (void*)p;
  };
  int*      cursor = (int*)alloc((size_t)NN * 4);
  float*    dinv   = (float*)alloc((size_t)NN * 4);
  ushort_t* bh     = (ushort_t*)alloc((size_t)DH * KP * 2);
  ushort_t* bl     = (ushort_t*)alloc((size_t)DH * KP * 2);
  int*      colsrc = (int*)alloc((size_t)NN * MAXDEG * 4);
  float*    hw     = (float*)alloc((size_t)NN * DH * 4);
  float*    hw2    = (float*)alloc((size_t)NN * DOUT * 4);

  hipMemsetAsync(cursor, 0, (size_t)NN * 4, stream);
  k_fill<<<(NE + NN + 255) / 256, 256, 0, stream>>>(ei, cursor, colsrc);
  k_dinv<<<(NN + 255) / 256, 256, 0, stream>>>(cursor, dinv);
  k_w1cvt<<<(DH * KP + 255) / 256, 256, 0, stream>>>(W1, bh, bl);
  k_gemm1<<<(NN / 16 + 3) / 4, 256, 0, stream>>>(x, bh, bl, hw);
  k_agg1<<<(NN + 3) / 4, 256, 0, stream>>>(hw, colsrc, cursor, dinv, b1, W2, hw2);
  k_agg2<<<(NN + 255) / 256, 256, 0, stream>>>(hw2, colsrc, cursor, dinv, b2, out);
}

// Round 2
// 317.584 us; speedup vs baseline: 1.4538x; 1.4538x over previous
//
#include <hip/hip_runtime.h>
#include <stdint.h>

#define NN 100000
#define NE 1600000
#define DIN 500
#define DH 64
#define DOUT 8
#define KP 512          // K padded to 16 mfma steps of 32
#define MAXDEG 64       // P(in-deg+self >= 64) ~ 1e-19 for Poisson(16)
#define LDSW 132        // LDS row stride in floats (128 + 4 pad -> 2-way = free)

typedef __attribute__((ext_vector_type(8))) short short8;
typedef __attribute__((ext_vector_type(4))) float f32x4;
typedef unsigned short ushort_t;

static __device__ __forceinline__ ushort_t f2bf(float f) {
  union { float f; uint32_t u; } v; v.f = f;
  uint32_t u = v.u;
  return (ushort_t)((u + 0x7FFFu + ((u >> 16) & 1u)) >> 16);  // RTN-even
}
static __device__ __forceinline__ float bf2f(ushort_t h) {
  union { uint32_t u; float f; } v; v.u = ((uint32_t)h) << 16;
  return v.f;
}

// Build fixed-stride reverse adjacency: colsrc[d*64 + slot] = s, cursor[d]=deg(incl self)
__global__ __launch_bounds__(256) void k_fill(const int* __restrict__ ei,
                                              int* __restrict__ cursor,
                                              int* __restrict__ colsrc) {
  int id = blockIdx.x * 256 + threadIdx.x;
  if (id >= NE + NN) return;
  int s, d;
  if (id < NE) { s = ei[id]; d = ei[NE + id]; }
  else { s = id - NE; d = s; }                 // self-loops
  int pos = atomicAdd(&cursor[d], 1);
  if (pos < MAXDEG) colsrc[d * MAXDEG + pos] = s;
}

__global__ __launch_bounds__(256) void k_dinv(const int* __restrict__ cursor,
                                              float* __restrict__ dinv) {
  int v = blockIdx.x * 256 + threadIdx.x;
  if (v >= NN) return;
  dinv[v] = 1.0f / sqrtf((float)cursor[v]);    // deg >= 1 always (self-loop)
}

// W1 -> bf16 hi/lo packed in EXACT per-lane B-fragment order:
// id = ((kkg*4 + off)*64 + lane)*8 + i ; col = off*16 + (lane&15); k = kkg*32 + (lane>>4)*8 + i
__global__ __launch_bounds__(256) void k_w1cvt(const float* __restrict__ W1,
                                               ushort_t* __restrict__ bh,
                                               ushort_t* __restrict__ bl) {
  int id = blockIdx.x * 256 + threadIdx.x;
  if (id >= DH * KP) return;
  int i = id & 7, lane = (id >> 3) & 63, off = (id >> 9) & 3, kkg = id >> 11;
  int r = lane & 15, g = lane >> 4;
  int col = off * 16 + r;
  int k = kkg * 32 + g * 8 + i;
  float v = (k < DIN) ? W1[k * DH + col] : 0.0f;
  ushort_t hi = f2bf(v);
  bh[id] = hi;
  bl[id] = f2bf(v - bf2f(hi));
}

// hw = x @ W1 via MFMA, LDS-staged x (coalesced HBM reads), bf16 output.
// Block = 256 thr = 4 waves = 64 rows; K chunked by 128 floats through LDS.
__global__ __launch_bounds__(256) void k_gemm1(const float* __restrict__ x,
                                               const ushort_t* __restrict__ bh,
                                               const ushort_t* __restrict__ bl,
                                               ushort_t* __restrict__ hwb) {
  __shared__ float lds[64 * LDSW];
  int tid = threadIdx.x;
  int lane = tid & 63, w = tid >> 6;
  int r = lane & 15, g = lane >> 4;
  int row0 = blockIdx.x * 64;

  f32x4 acc0 = {0,0,0,0}, acc1 = {0,0,0,0}, acc2 = {0,0,0,0}, acc3 = {0,0,0,0};

  for (int ch = 0; ch < 4; ++ch) {
    __syncthreads();                       // protect previous chunk's reads
#pragma unroll
    for (int j = 0; j < 8; ++j) {          // 64 rows x 32 quads, coalesced 512B runs
      int idx = j * 256 + tid;
      int lr = idx >> 5;
      int pos = idx & 31;
      int kq = ch * 32 + pos;              // global quad index (125 per row)
      float4 val = {0, 0, 0, 0};
      int grow = row0 + lr;
      if (kq < 125 && grow < NN)
        val = *(const float4*)(x + (size_t)grow * DIN + kq * 4);
      *(float4*)(&lds[lr * LDSW + pos * 4]) = val;
    }
    __syncthreads();
#pragma unroll
    for (int kk = 0; kk < 4; ++kk) {
      int kb = kk * 32 + g * 8;
      const float* lp = &lds[(w * 16 + r) * LDSW + kb];
      float4 v0 = *(const float4*)lp;
      float4 v1 = *(const float4*)(lp + 4);
      float a[8] = {v0.x, v0.y, v0.z, v0.w, v1.x, v1.y, v1.z, v1.w};
      short8 ah, al;
#pragma unroll
      for (int i = 0; i < 8; ++i) {
        ushort_t hi = f2bf(a[i]);
        ah[i] = (short)hi;
        al[i] = (short)f2bf(a[i] - bf2f(hi));
      }
      int kkg = ch * 4 + kk;
      const ushort_t* bph = bh + (size_t)(kkg * 4) * 512 + lane * 8;
      const ushort_t* bpl = bl + (size_t)(kkg * 4) * 512 + lane * 8;
#define TILE(T, OFF)                                                            \
      {                                                                         \
        short8 bhf = *(const short8*)(bph + (OFF) * 512);                       \
        short8 blf = *(const short8*)(bpl + (OFF) * 512);                       \
        T = __builtin_amdgcn_mfma_f32_16x16x32_bf16(ah, bhf, T, 0, 0, 0);       \
        T = __builtin_amdgcn_mfma_f32_16x16x32_bf16(al, bhf, T, 0, 0, 0);       \
        T = __builtin_amdgcn_mfma_f32_16x16x32_bf16(ah, blf, T, 0, 0, 0);       \
      }
      TILE(acc0, 0) TILE(acc1, 1) TILE(acc2, 2) TILE(acc3, 3)
#undef TILE
    }
  }
  int wrow0 = row0 + w * 16;
#pragma unroll
  for (int i = 0; i < 4; ++i) {
    int orow = wrow0 + g * 4 + i;          // C/D: row=(lane>>4)*4+reg, col=lane&15
    if (orow < NN) {
      ushort_t* o = hwb + (size_t)orow * DH + r;
      o[0]  = f2bf(acc0[i]);
      o[16] = f2bf(acc1[i]);
      o[32] = f2bf(acc2[i]);
      o[48] = f2bf(acc3[i]);
    }
  }
}

// Layer-1 aggregate (gather, pipelined 8-deep) + bias + ReLU + fused h@W2 -> hw2[v][0..7]
__global__ __launch_bounds__(256) void k_agg1(const ushort_t* __restrict__ hwb,
                                              const int* __restrict__ colsrc,
                                              const int* __restrict__ cnt,
                                              const float* __restrict__ dinv,
                                              const float* __restrict__ b1,
                                              const float* __restrict__ W2,
                                              float* __restrict__ hw2) {
  int lane = threadIdx.x & 63;
  int v = blockIdx.x * 4 + (threadIdx.x >> 6);
  if (v >= NN) return;
  int c = cnt[v]; if (c > MAXDEG) c = MAXDEG;
  float dv = dinv[v];
  const int* cl = colsrc + v * MAXDEG;
  int si = cl[lane];                        // one coalesced 256B adjacency read
  bool act = lane < c;
  if (!act) si = 0;
  float nrmv = act ? dinv[si] * dv : 0.0f;  // one gather for all edge norms
  float acc = 0.0f;
  for (int i0 = 0; i0 < c; i0 += 8) {       // 8 independent gathers in flight
    float val[8];
#pragma unroll
    for (int j = 0; j < 8; ++j) {
      int s = __builtin_amdgcn_readlane(si, i0 + j);
      val[j] = bf2f(hwb[(size_t)s * DH + lane]);   // 128B coalesced per edge
    }
#pragma unroll
    for (int j = 0; j < 8; ++j) {
      float nrm = __uint_as_float(__builtin_amdgcn_readlane(__float_as_uint(nrmv), i0 + j));
      acc = fmaf(val[j], nrm, acc);
    }
  }
  float h = acc + b1[lane];
  h = h > 0.0f ? h : 0.0f;
  const float* w2r = W2 + lane * DOUT;
  float p0 = h * w2r[0], p1 = h * w2r[1], p2 = h * w2r[2], p3 = h * w2r[3];
  float p4 = h * w2r[4], p5 = h * w2r[5], p6 = h * w2r[6], p7 = h * w2r[7];
#pragma unroll
  for (int off = 32; off > 0; off >>= 1) {
    p0 += __shfl_xor(p0, off); p1 += __shfl_xor(p1, off);
    p2 += __shfl_xor(p2, off); p3 += __shfl_xor(p3, off);
    p4 += __shfl_xor(p4, off); p5 += __shfl_xor(p5, off);
    p6 += __shfl_xor(p6, off); p7 += __shfl_xor(p7, off);
  }
  if (lane == 0) {
    float4 q0 = {p0, p1, p2, p3}, q1 = {p4, p5, p6, p7};
    *(float4*)(hw2 + (size_t)v * DOUT)     = q0;
    *(float4*)(hw2 + (size_t)v * DOUT + 4) = q1;
  }
}

// Layer-2 aggregate + bias + log_softmax. One WAVE per node: lanes = 8 edges x 8 features.
__global__ __launch_bounds__(256) void k_agg2(const float* __restrict__ hw2,
                                              const int* __restrict__ colsrc,
                                              const int* __restrict__ cnt,
                                              const float* __restrict__ dinv,
                                              const float* __restrict__ b2,
                                              float* __restrict__ out) {
  int lane = threadIdx.x & 63;
  int v = blockIdx.x * 4 + (threadIdx.x >> 6);
  if (v >= NN) return;
  int e = lane >> 3, f = lane & 7;
  int c = cnt[v]; if (c > MAXDEG) c = MAXDEG;
  float dv = dinv[v];
  const int* cl = colsrc + v * MAXDEG;
  float acc = 0.0f;
  for (int i0 = 0; i0 < c; i0 += 8) {       // 8 edges in parallel across lane groups
    int i = i0 + e;
    bool a2 = i < c;
    int s = a2 ? cl[i] : 0;
    float nrm = a2 ? dinv[s] * dv : 0.0f;
    float val = hw2[(size_t)s * DOUT + f] * nrm;
    val += __shfl_xor(val, 8);
    val += __shfl_xor(val, 16);
    val += __shfl_xor(val, 32);
    acc += val;
  }
  acc += b2[f];
  float m = acc;
  m = fmaxf(m, __shfl_xor(m, 1));
  m = fmaxf(m, __shfl_xor(m, 2));
  m = fmaxf(m, __shfl_xor(m, 4));
  float ex = expf(acc - m);
  float sum = ex;
  sum += __shfl_xor(sum, 1);
  sum += __shfl_xor(sum, 2);
  sum += __shfl_xor(sum, 4);
  float ls = m + logf(sum);
  if (e == 0) out[(size_t)v * DOUT + f] = acc - ls;
}

extern "C" void kernel_launch(void* const* d_in, const int* in_sizes, int n_in,
                              void* d_out, int out_size, void* d_ws, size_t ws_size,
                              hipStream_t stream) {
  const float* x  = (const float*)d_in[0];
  const int*   ei = (const int*)d_in[1];
  const float* W1 = (const float*)d_in[2];
  const float* b1 = (const float*)d_in[3];
  const float* W2 = (const float*)d_in[4];
  const float* b2 = (const float*)d_in[5];
  float* out = (float*)d_out;

  char* w = (char*)d_ws;
  size_t off = 0;
  auto alloc = [&](size_t bytes) {
    char* p = w + off;
    off += (bytes + 255) & ~(size_t)255;
    return (void*)p;
  };
  int*      cursor = (int*)alloc((size_t)NN * 4);
  float*    dinv   = (float*)alloc((size_t)NN * 4);
  ushort_t* bh     = (ushort_t*)alloc((size_t)DH * KP * 2);
  ushort_t* bl     = (ushort_t*)alloc((size_t)DH * KP * 2);
  int*      colsrc = (int*)alloc((size_t)NN * MAXDEG * 4);
  ushort_t* hwb    = (ushort_t*)alloc((size_t)NN * DH * 2);
  float*    hw2    = (float*)alloc((size_t)NN * DOUT * 4);

  hipMemsetAsync(cursor, 0, (size_t)NN * 4, stream);
  k_fill<<<(NE + NN + 255) / 256, 256, 0, stream>>>(ei, cursor, colsrc);
  k_dinv<<<(NN + 255) / 256, 256, 0, stream>>>(cursor, dinv);
  k_w1cvt<<<(DH * KP + 255) / 256, 256, 0, stream>>>(W1, bh, bl);
  k_gemm1<<<(NN + 63) / 64, 256, 0, stream>>>(x, bh, bl, hwb);
  k_agg1<<<(NN + 3) / 4, 256, 0, stream>>>(hwb, colsrc, cursor, dinv, b1, W2, hw2);
  k_agg2<<<(NN + 3) / 4, 256, 0, stream>>>(hw2, colsrc, cursor, dinv, b2, out);
}

// Round 3
// 263.047 us; speedup vs baseline: 1.7552x; 1.2073x over previous
//
#include <hip/hip_runtime.h>
#include <stdint.h>

#define NN 100000
#define NE 1600000
#define DIN 500
#define DH 64
#define DOUT 8
#define KP 512          // K padded to 16 mfma steps of 32
#define MAXDEG 64       // P(in-deg+self >= 64) ~ 1e-19 for Poisson(17)
#define LDSW 132        // LDS row stride in floats (128 + 4 pad -> 2-way = free)

#define FILL_EPT 4
#define FILL_PASSES 16
#define FILL_RS ((NN + FILL_PASSES - 1) / FILL_PASSES)   // 6250 nodes per pass

typedef __attribute__((ext_vector_type(8))) short short8;
typedef __attribute__((ext_vector_type(4))) float f32x4;
typedef unsigned short ushort_t;

static __device__ __forceinline__ ushort_t f2bf(float f) {
  union { float f; uint32_t u; } v; v.f = f;
  uint32_t u = v.u;
  return (ushort_t)((u + 0x7FFFu + ((u >> 16) & 1u)) >> 16);  // RTN-even
}
static __device__ __forceinline__ float bf2f(ushort_t h) {
  union { uint32_t u; float f; } v; v.u = ((uint32_t)h) << 16;
  return v.f;
}

// Build fixed-stride reverse adjacency with dst-range passes for L2 write merge.
// Edges cached in registers (one coalesced read); 16 passes over dst ranges so the
// active colsrc slice (1.6 MB) stays L2-resident and 4B stores merge before writeback.
__global__ __launch_bounds__(256) void k_fill(const int* __restrict__ ei,
                                              int* __restrict__ cursor,
                                              int* __restrict__ colsrc) {
  int t = blockIdx.x * 256 + threadIdx.x;
  const int T = gridDim.x * 256;
  int s[FILL_EPT], d[FILL_EPT];
#pragma unroll
  for (int k = 0; k < FILL_EPT; ++k) {
    int id = t + k * T;
    s[k] = 0; d[k] = -1;                       // -1 never matches any pass range
    if (id < NE) { s[k] = ei[id]; d[k] = ei[NE + id]; }
    else if (id < NE + NN) { s[k] = id - NE; d[k] = s[k]; }   // self-loops
  }
#pragma unroll 1
  for (int p = 0; p < FILL_PASSES; ++p) {
    int lo = p * FILL_RS;
    int hi = lo + FILL_RS;
#pragma unroll
    for (int k = 0; k < FILL_EPT; ++k) {
      bool act = (d[k] >= lo) && (d[k] < hi);
      if (__any(act)) {
        if (act) {
          int pos = atomicAdd(&cursor[d[k]], 1);
          if (pos < MAXDEG) colsrc[d[k] * MAXDEG + pos] = s[k];
        }
      }
    }
  }
}

__global__ __launch_bounds__(256) void k_dinv(const int* __restrict__ cursor,
                                              float* __restrict__ dinv) {
  int v = blockIdx.x * 256 + threadIdx.x;
  if (v >= NN) return;
  dinv[v] = 1.0f / sqrtf((float)cursor[v]);    // deg >= 1 always (self-loop)
}

// W1 -> bf16 hi/lo packed in EXACT per-lane B-fragment order:
// id = ((kkg*4 + off)*64 + lane)*8 + i ; col = off*16 + (lane&15); k = kkg*32 + (lane>>4)*8 + i
__global__ __launch_bounds__(256) void k_w1cvt(const float* __restrict__ W1,
                                               ushort_t* __restrict__ bh,
                                               ushort_t* __restrict__ bl) {
  int id = blockIdx.x * 256 + threadIdx.x;
  if (id >= DH * KP) return;
  int i = id & 7, lane = (id >> 3) & 63, off = (id >> 9) & 3, kkg = id >> 11;
  int r = lane & 15, g = lane >> 4;
  int col = off * 16 + r;
  int k = kkg * 32 + g * 8 + i;
  float v = (k < DIN) ? W1[k * DH + col] : 0.0f;
  ushort_t hi = f2bf(v);
  bh[id] = hi;
  bl[id] = f2bf(v - bf2f(hi));
}

// hw = x @ W1 via MFMA, LDS-staged x (coalesced HBM reads), bf16 output.
// Block = 256 thr = 4 waves = 64 rows; K chunked by 128 floats through LDS.
__global__ __launch_bounds__(256) void k_gemm1(const float* __restrict__ x,
                                               const ushort_t* __restrict__ bh,
                                               const ushort_t* __restrict__ bl,
                                               ushort_t* __restrict__ hwb) {
  __shared__ float lds[64 * LDSW];
  int tid = threadIdx.x;
  int lane = tid & 63, w = tid >> 6;
  int r = lane & 15, g = lane >> 4;
  int row0 = blockIdx.x * 64;

  f32x4 acc0 = {0,0,0,0}, acc1 = {0,0,0,0}, acc2 = {0,0,0,0}, acc3 = {0,0,0,0};

  for (int ch = 0; ch < 4; ++ch) {
    __syncthreads();                       // protect previous chunk's reads
#pragma unroll
    for (int j = 0; j < 8; ++j) {          // 64 rows x 32 quads, coalesced 512B runs
      int idx = j * 256 + tid;
      int lr = idx >> 5;
      int pos = idx & 31;
      int kq = ch * 32 + pos;              // global quad index (125 per row)
      float4 val = {0, 0, 0, 0};
      int grow = row0 + lr;
      if (kq < 125 && grow < NN)
        val = *(const float4*)(x + (size_t)grow * DIN + kq * 4);
      *(float4*)(&lds[lr * LDSW + pos * 4]) = val;
    }
    __syncthreads();
#pragma unroll
    for (int kk = 0; kk < 4; ++kk) {
      int kb = kk * 32 + g * 8;
      const float* lp = &lds[(w * 16 + r) * LDSW + kb];
      float4 v0 = *(const float4*)lp;
      float4 v1 = *(const float4*)(lp + 4);
      float a[8] = {v0.x, v0.y, v0.z, v0.w, v1.x, v1.y, v1.z, v1.w};
      short8 ah, al;
#pragma unroll
      for (int i = 0; i < 8; ++i) {
        ushort_t hi = f2bf(a[i]);
        ah[i] = (short)hi;
        al[i] = (short)f2bf(a[i] - bf2f(hi));
      }
      int kkg = ch * 4 + kk;
      const ushort_t* bph = bh + (size_t)(kkg * 4) * 512 + lane * 8;
      const ushort_t* bpl = bl + (size_t)(kkg * 4) * 512 + lane * 8;
#define TILE(T, OFF)                                                            \
      {                                                                         \
        short8 bhf = *(const short8*)(bph + (OFF) * 512);                       \
        short8 blf = *(const short8*)(bpl + (OFF) * 512);                       \
        T = __builtin_amdgcn_mfma_f32_16x16x32_bf16(ah, bhf, T, 0, 0, 0);       \
        T = __builtin_amdgcn_mfma_f32_16x16x32_bf16(al, bhf, T, 0, 0, 0);       \
        T = __builtin_amdgcn_mfma_f32_16x16x32_bf16(ah, blf, T, 0, 0, 0);       \
      }
      TILE(acc0, 0) TILE(acc1, 1) TILE(acc2, 2) TILE(acc3, 3)
#undef TILE
    }
  }
  int wrow0 = row0 + w * 16;
#pragma unroll
  for (int i = 0; i < 4; ++i) {
    int orow = wrow0 + g * 4 + i;          // C/D: row=(lane>>4)*4+reg, col=lane&15
    if (orow < NN) {
      ushort_t* o = hwb + (size_t)orow * DH + r;
      o[0]  = f2bf(acc0[i]);
      o[16] = f2bf(acc1[i]);
      o[32] = f2bf(acc2[i]);
      o[48] = f2bf(acc3[i]);
    }
  }
}

// Layer-1 aggregate (gather, pipelined 8-deep) + bias + ReLU + fused h@W2 -> hw2[v][0..7]
__global__ __launch_bounds__(256) void k_agg1(const ushort_t* __restrict__ hwb,
                                              const int* __restrict__ colsrc,
                                              const int* __restrict__ cnt,
                                              const float* __restrict__ dinv,
                                              const float* __restrict__ b1,
                                              const float* __restrict__ W2,
                                              float* __restrict__ hw2) {
  int lane = threadIdx.x & 63;
  int v = blockIdx.x * 4 + (threadIdx.x >> 6);
  if (v >= NN) return;
  int c = cnt[v]; if (c > MAXDEG) c = MAXDEG;
  float dv = dinv[v];
  const int* cl = colsrc + v * MAXDEG;
  int si = cl[lane];                        // one coalesced 256B adjacency read
  bool act = lane < c;
  if (!act) si = 0;
  float nrmv = act ? dinv[si] * dv : 0.0f;  // one gather for all edge norms
  float acc = 0.0f;
  for (int i0 = 0; i0 < c; i0 += 8) {       // 8 independent gathers in flight
    float val[8];
#pragma unroll
    for (int j = 0; j < 8; ++j) {
      int s = __builtin_amdgcn_readlane(si, i0 + j);
      val[j] = bf2f(hwb[(size_t)s * DH + lane]);   // 128B coalesced per edge
    }
#pragma unroll
    for (int j = 0; j < 8; ++j) {
      float nrm = __uint_as_float(__builtin_amdgcn_readlane(__float_as_uint(nrmv), i0 + j));
      acc = fmaf(val[j], nrm, acc);
    }
  }
  float h = acc + b1[lane];
  h = h > 0.0f ? h : 0.0f;
  const float* w2r = W2 + lane * DOUT;
  float p0 = h * w2r[0], p1 = h * w2r[1], p2 = h * w2r[2], p3 = h * w2r[3];
  float p4 = h * w2r[4], p5 = h * w2r[5], p6 = h * w2r[6], p7 = h * w2r[7];
#pragma unroll
  for (int off = 32; off > 0; off >>= 1) {
    p0 += __shfl_xor(p0, off); p1 += __shfl_xor(p1, off);
    p2 += __shfl_xor(p2, off); p3 += __shfl_xor(p3, off);
    p4 += __shfl_xor(p4, off); p5 += __shfl_xor(p5, off);
    p6 += __shfl_xor(p6, off); p7 += __shfl_xor(p7, off);
  }
  if (lane == 0) {
    float4 q0 = {p0, p1, p2, p3}, q1 = {p4, p5, p6, p7};
    *(float4*)(hw2 + (size_t)v * DOUT)     = q0;
    *(float4*)(hw2 + (size_t)v * DOUT + 4) = q1;
  }
}

// Layer-2 aggregate + bias + log_softmax. One WAVE per node: lanes = 8 edges x 8 features.
__global__ __launch_bounds__(256) void k_agg2(const float* __restrict__ hw2,
                                              const int* __restrict__ colsrc,
                                              const int* __restrict__ cnt,
                                              const float* __restrict__ dinv,
                                              const float* __restrict__ b2,
                                              float* __restrict__ out) {
  int lane = threadIdx.x & 63;
  int v = blockIdx.x * 4 + (threadIdx.x >> 6);
  if (v >= NN) return;
  int e = lane >> 3, f = lane & 7;
  int c = cnt[v]; if (c > MAXDEG) c = MAXDEG;
  float dv = dinv[v];
  const int* cl = colsrc + v * MAXDEG;
  float acc = 0.0f;
  for (int i0 = 0; i0 < c; i0 += 8) {       // 8 edges in parallel across lane groups
    int i = i0 + e;
    bool a2 = i < c;
    int s = a2 ? cl[i] : 0;
    float nrm = a2 ? dinv[s] * dv : 0.0f;
    float val = hw2[(size_t)s * DOUT + f] * nrm;
    val += __shfl_xor(val, 8);
    val += __shfl_xor(val, 16);
    val += __shfl_xor(val, 32);
    acc += val;
  }
  acc += b2[f];
  float m = acc;
  m = fmaxf(m, __shfl_xor(m, 1));
  m = fmaxf(m, __shfl_xor(m, 2));
  m = fmaxf(m, __shfl_xor(m, 4));
  float ex = expf(acc - m);
  float sum = ex;
  sum += __shfl_xor(sum, 1);
  sum += __shfl_xor(sum, 2);
  sum += __shfl_xor(sum, 4);
  float ls = m + logf(sum);
  if (e == 0) out[(size_t)v * DOUT + f] = acc - ls;
}

extern "C" void kernel_launch(void* const* d_in, const int* in_sizes, int n_in,
                              void* d_out, int out_size, void* d_ws, size_t ws_size,
                              hipStream_t stream) {
  const float* x  = (const float*)d_in[0];
  const int*   ei = (const int*)d_in[1];
  const float* W1 = (const float*)d_in[2];
  const float* b1 = (const float*)d_in[3];
  const float* W2 = (const float*)d_in[4];
  const float* b2 = (const float*)d_in[5];
  float* out = (float*)d_out;

  char* w = (char*)d_ws;
  size_t off = 0;
  auto alloc = [&](size_t bytes) {
    char* p = w + off;
    off += (bytes + 255) & ~(size_t)255;
    return (void*)p;
  };
  int*      cursor = (int*)alloc((size_t)NN * 4);
  float*    dinv   = (float*)alloc((size_t)NN * 4);
  ushort_t* bh     = (ushort_t*)alloc((size_t)DH * KP * 2);
  ushort_t* bl     = (ushort_t*)alloc((size_t)DH * KP * 2);
  int*      colsrc = (int*)alloc((size_t)NN * MAXDEG * 4);
  ushort_t* hwb    = (ushort_t*)alloc((size_t)NN * DH * 2);
  float*    hw2    = (float*)alloc((size_t)NN * DOUT * 4);

  hipMemsetAsync(cursor, 0, (size_t)NN * 4, stream);
  int fill_blocks = (NE + NN + 256 * FILL_EPT - 1) / (256 * FILL_EPT);  // 1661: all co-resident
  k_fill<<<fill_blocks, 256, 0, stream>>>(ei, cursor, colsrc);
  k_dinv<<<(NN + 255) / 256, 256, 0, stream>>>(cursor, dinv);
  k_w1cvt<<<(DH * KP + 255) / 256, 256, 0, stream>>>(W1, bh, bl);
  k_gemm1<<<(NN + 63) / 64, 256, 0, stream>>>(x, bh, bl, hwb);
  k_agg1<<<(NN + 3) / 4, 256, 0, stream>>>(hwb, colsrc, cursor, dinv, b1, W2, hw2);
  k_agg2<<<(NN + 3) / 4, 256, 0, stream>>>(hw2, colsrc, cursor, dinv, b2, out);
}